// Round 5
// baseline (159.849 us; speedup 1.0000x reference)
//
#include <hip/hip_runtime.h>
#include <cmath>

#define NN 20000
#define DD 256
#define KK 16
#define LDC3 768   // combined row: [s(0..255) | u(256..511) | t(512..767)]

typedef __attribute__((ext_vector_type(8))) short short8;
typedef __attribute__((ext_vector_type(4))) float f32x4;
typedef unsigned int u32;
typedef unsigned short bfu;

__device__ __forceinline__ float b2f(bfu u) {
  union { u32 i; float f; } v; v.i = ((u32)u) << 16; return v.f;
}
__device__ __forceinline__ bfu f2b(float f) {
  u32 u = __float_as_uint(f);
  u = (u + 0x7fff + ((u >> 16) & 1)) >> 16;
  return (bfu)u;
}
__device__ __forceinline__ float wave_sum(float v) {
#pragma unroll
  for (int m = 32; m; m >>= 1) v += __shfl_xor(v, m, 64);
  return v;
}
__device__ __forceinline__ void gl_lds16(const void* g, void* l) {
  __builtin_amdgcn_global_load_lds((const __attribute__((address_space(1))) u32*)g,
                                   (__attribute__((address_space(3))) u32*)l, 16, 0, 0);
}

// -------- prep: LayerNorm (blocks 0..4999) + weight f32->bf16 (blocks 5000+) -----
__global__ __launch_bounds__(256) void prep_kernel(
    const float* __restrict__ x, const float* __restrict__ g,
    const float* __restrict__ b, const float* __restrict__ Wself,
    const float* __restrict__ Wnei, const float* __restrict__ Wred,
    bfu* __restrict__ C3, bfu* __restrict__ Wcat, bfu* __restrict__ Wredb) {
  int bid = blockIdx.x;
  if (bid < 5000) {
    int lane = threadIdx.x & 63;
    int row = (bid << 2) + (threadIdx.x >> 6);
    float4 v = ((const float4*)(x + (size_t)row * DD))[lane];
    float mean = wave_sum(v.x + v.y + v.z + v.w) * (1.0f / 256.0f);
    float4 d = make_float4(v.x - mean, v.y - mean, v.z - mean, v.w - mean);
    float var = wave_sum(d.x * d.x + d.y * d.y + d.z * d.z + d.w * d.w) * (1.0f / 256.0f);
    float rstd = 1.0f / sqrtf(var + 1e-5f);
    float4 g4 = ((const float4*)g)[lane];
    float4 b4 = ((const float4*)b)[lane];
    ushort4 ov;
    ov.x = f2b(d.x * rstd * g4.x + b4.x);
    ov.y = f2b(d.y * rstd * g4.y + b4.y);
    ov.z = f2b(d.z * rstd * g4.z + b4.z);
    ov.w = f2b(d.w * rstd * g4.w + b4.w);
    *(ushort4*)(C3 + (size_t)row * LDC3 + 512 + (lane << 2)) = ov;
  } else {
    int idx = (bid - 5000) * 256 + threadIdx.x;
    if (idx < 65536) Wcat[idx] = f2b(Wself[idx]);
    else if (idx < 131072) Wcat[idx] = f2b(Wnei[idx - 65536]);
    else if (idx < 147456) Wredb[idx - 131072] = f2b(Wred[idx - 131072]);
  }
}

// -------- bf16 MFMA GEMM, 2-phase double-buffered LDS pipeline -------------------
// C[m, nbase+n] = A[m,:(256)] . W[nbase+n,:] + bias. Swapped-operand MFMA so each
// lane holds 4 consecutive output cols (vectorized C store).
template<int NT, bool FINAL>
__global__ __launch_bounds__(256) void gemm_kernel(
    const bfu* __restrict__ A, int lda, const bfu* __restrict__ Bw,
    const float* __restrict__ bias0, const float* __restrict__ bias1,
    void* __restrict__ Cout, int ldc, int M) {
  constexpr int FM = (NT == 128) ? 4 : 2;
  constexpr int WM = (NT == 128) ? 64 : 32;
  constexpr int AIT = 4;         // 128 rows * 8 chunks / 256 threads
  constexpr int BIT = NT / 32;   // NT   rows * 8 chunks / 256 threads
  __shared__ bfu smA[2][128 * 64];
  __shared__ bfu smB[2][NT * 64];
  int tid = threadIdx.x, lane = tid & 63, wid = tid >> 6;
  int m0 = blockIdx.x * 128;
  int nbase = blockIdx.y * NT;
  const bfu* Bt = Bw + (size_t)nbase * 256;
  int wr = (NT == 128) ? (wid >> 1) : wid;
  int wc = (NT == 128) ? (wid & 1) : 0;
  int lr = lane & 15, lk = lane >> 4;

  f32x4 acc[FM][4];
#pragma unroll
  for (int i = 0; i < FM; ++i)
#pragma unroll
    for (int j = 0; j < 4; ++j) acc[i][j] = (f32x4){0.f, 0.f, 0.f, 0.f};

#define STAGE(buf, kc)                                                          \
  {                                                                             \
    _Pragma("unroll") for (int i = 0; i < AIT; ++i) {                           \
      int p = tid + 256 * i; int row = p >> 3; int c = (p & 7) ^ (row & 7);     \
      gl_lds16(A + (size_t)(m0 + row) * lda + (kc) + c * 8, &smA[buf][p * 8]);  \
    }                                                                           \
    _Pragma("unroll") for (int i = 0; i < BIT; ++i) {                           \
      int p = tid + 256 * i; int row = p >> 3; int c = (p & 7) ^ (row & 7);     \
      gl_lds16(Bt + (size_t)row * 256 + (kc) + c * 8, &smB[buf][p * 8]);        \
    }                                                                           \
  }

#define COMPUTE(buf)                                                            \
  {                                                                             \
    _Pragma("unroll") for (int h = 0; h < 2; ++h) {                             \
      short8 af[FM], bfr[4];                                                    \
      int cc = h * 4 + lk;                                                      \
      _Pragma("unroll") for (int fm = 0; fm < FM; ++fm) {                       \
        int row = wr * WM + fm * 16 + lr;                                       \
        af[fm] = *(const short8*)&smA[buf][row * 64 + ((cc ^ (row & 7)) << 3)]; \
      }                                                                         \
      _Pragma("unroll") for (int fn = 0; fn < 4; ++fn) {                        \
        int row = wc * 64 + fn * 16 + lr;                                       \
        bfr[fn] = *(const short8*)&smB[buf][row * 64 + ((cc ^ (row & 7)) << 3)];\
      }                                                                         \
      _Pragma("unroll") for (int fm = 0; fm < FM; ++fm)                         \
        _Pragma("unroll") for (int fn = 0; fn < 4; ++fn)                        \
          acc[fm][fn] = __builtin_amdgcn_mfma_f32_16x16x32_bf16(                \
              bfr[fn], af[fm], acc[fm][fn], 0, 0, 0);                           \
    }                                                                           \
  }

  // 2-phase pipeline, fully unrolled over K=256 (4 steps of BK=64):
  // barrier -> issue next-tile loads -> compute current (loads in flight).
  STAGE(0, 0);
  __syncthreads();          // compiler emits vmcnt(0) drain before s_barrier
  STAGE(1, 64);
  COMPUTE(0);
  __syncthreads();
  STAGE(0, 128);
  COMPUTE(1);
  __syncthreads();
  STAGE(1, 192);
  COMPUTE(0);
  __syncthreads();
  COMPUTE(1);
#undef STAGE
#undef COMPUTE

  const float* bias = (nbase < 256) ? (bias0 + nbase) : (bias1 + (nbase - 256));
#pragma unroll
  for (int fm = 0; fm < FM; ++fm) {
    int m = m0 + wr * WM + fm * 16 + lr;
    if (m >= M) continue;
#pragma unroll
    for (int fn = 0; fn < 4; ++fn) {
      int lc = wc * 64 + fn * 16 + lk * 4;     // col offset within tile
      float4 bv = *(const float4*)(bias + lc);
      float o0 = acc[fm][fn][0] + bv.x;
      float o1 = acc[fm][fn][1] + bv.y;
      float o2 = acc[fm][fn][2] + bv.z;
      float o3 = acc[fm][fn][3] + bv.w;
      if (FINAL) {
        o0 = (o0 > 0.f) ? o0 : 0.01f * o0; o0 = (o0 > 0.f) ? o0 : 0.01f * o0;
        o1 = (o1 > 0.f) ? o1 : 0.01f * o1; o1 = (o1 > 0.f) ? o1 : 0.01f * o1;
        o2 = (o2 > 0.f) ? o2 : 0.01f * o2; o2 = (o2 > 0.f) ? o2 : 0.01f * o2;
        o3 = (o3 > 0.f) ? o3 : 0.01f * o3; o3 = (o3 > 0.f) ? o3 : 0.01f * o3;
        *(float4*)((float*)Cout + (size_t)m * ldc + nbase + lc) =
            make_float4(o0, o1, o2, o3);
      } else {
        ushort4 ov; ov.x = f2b(o0); ov.y = f2b(o1); ov.z = f2b(o2); ov.w = f2b(o3);
        *(ushort4*)((bfu*)Cout + (size_t)m * ldc + nbase + lc) = ov;
      }
    }
  }
}

// -------- gather + softmax(17) + threshold + context; single fused k-loop --------
__global__ __launch_bounds__(256) void gather_kernel(
    const bfu* __restrict__ C3, const float* __restrict__ coords,
    const int* __restrict__ col, const float* __restrict__ bmix,
    bfu* __restrict__ ctx) {
  const float L2E = 1.4426950408889634f;
  int lane = threadIdx.x & 63;
  int i = (blockIdx.x << 2) + (threadIdx.x >> 6);
  float beta = bmix[0];

  int ck = col[i * KK + (lane & 15)];
  float2 ci = ((const float2*)coords)[i];
  float2 cn = ((const float2*)coords)[ck];
  float dx = ci.x - cn.x, dy = ci.y - cn.y;
  // dist weight, then pre-scale by log2(e) so softmax exp becomes one v_exp each
  float dwv = exp2f((-2.0f * L2E / (50.0f + 1e-8f)) * sqrtf(dx * dx + dy * dy)) * L2E;

  int d = lane << 2;
  const bfu* rowi = C3 + (size_t)i * LDC3;
  ushort4 sv = *(const ushort4*)(rowi + d);
  float4 e0 = make_float4(exp2f(L2E * b2f(sv.x)), exp2f(L2E * b2f(sv.y)),
                          exp2f(L2E * b2f(sv.z)), exp2f(L2E * b2f(sv.w)));
  float4 Z = e0;
  float4 ef[KK];
  ushort4 tn[KK];
#pragma unroll
  for (int k = 0; k < KK; ++k) {
    int cc = __shfl(ck, k, 64);
    float w = __shfl(dwv, k, 64);
    const bfu* rowc = C3 + (size_t)cc * LDC3;
    ushort4 uv = *(const ushort4*)(rowc + 256 + d);
    tn[k] = *(const ushort4*)(rowc + 512 + d);
    float4 e = make_float4(exp2f(w * b2f(uv.x)), exp2f(w * b2f(uv.y)),
                           exp2f(w * b2f(uv.z)), exp2f(w * b2f(uv.w)));
    ef[k] = e;
    Z.x += e.x; Z.y += e.y; Z.z += e.z; Z.w += e.w;
  }
  // threshold on weight w=e/Z >= 0.01  <=>  e >= 0.01*Z  (weights positive)
  float4 thr = make_float4(0.01f * Z.x, 0.01f * Z.y, 0.01f * Z.z, 0.01f * Z.w);
  ushort4 tv = *(const ushort4*)(rowi + 512 + d);
  float ob = 1.0f - beta;
  float4 ns = make_float4(0.f, 0.f, 0.f, 0.f);
#pragma unroll
  for (int k = 0; k < KK; ++k) {
    float ex = (ef[k].x >= thr.x) ? ef[k].x : 0.f;
    float ey = (ef[k].y >= thr.y) ? ef[k].y : 0.f;
    float ez = (ef[k].z >= thr.z) ? ef[k].z : 0.f;
    float ew = (ef[k].w >= thr.w) ? ef[k].w : 0.f;
    ns.x += ex * b2f(tn[k].x); ns.y += ey * b2f(tn[k].y);
    ns.z += ez * b2f(tn[k].z); ns.w += ew * b2f(tn[k].w);
  }
  float s0x = (e0.x >= thr.x) ? e0.x : 0.f;
  float s0y = (e0.y >= thr.y) ? e0.y : 0.f;
  float s0z = (e0.z >= thr.z) ? e0.z : 0.f;
  float s0w = (e0.w >= thr.w) ? e0.w : 0.f;
  ushort4 ov;
  ov.x = f2b((beta * s0x * b2f(tv.x) + ob * ns.x) / Z.x);
  ov.y = f2b((beta * s0y * b2f(tv.y) + ob * ns.y) / Z.y);
  ov.z = f2b((beta * s0z * b2f(tv.z) + ob * ns.z) / Z.z);
  ov.w = f2b((beta * s0w * b2f(tv.w) + ob * ns.w) / Z.w);
  *(ushort4*)(ctx + (size_t)i * DD + d) = ov;
}

extern "C" void kernel_launch(void* const* d_in, const int* in_sizes, int n_in,
                              void* d_out, int out_size, void* d_ws, size_t ws_size,
                              hipStream_t stream) {
  (void)in_sizes; (void)n_in; (void)out_size; (void)ws_size;
  const float* x       = (const float*)d_in[0];
  const float* coords  = (const float*)d_in[1];
  const float* gamma   = (const float*)d_in[2];
  const float* beta_ln = (const float*)d_in[3];
  const float* W_self  = (const float*)d_in[4];
  const float* b_self  = (const float*)d_in[5];
  const float* W_nei   = (const float*)d_in[6];
  const float* b_nei   = (const float*)d_in[7];
  const float* W_red   = (const float*)d_in[8];
  const float* b_red   = (const float*)d_in[9];
  const float* bmix    = (const float*)d_in[10];
  const int*   edge    = (const int*)d_in[11];
  const int*   col     = edge + (size_t)NN * KK;

  // workspace layout (20096 rows to absorb last-tile OOB reads harmlessly)
  bfu* C3    = (bfu*)d_ws;                              // 20096*768*2 = 30,867,456
  bfu* ctx   = (bfu*)((char*)d_ws + 30867456);          // 20096*256*2 = 10,289,152
  bfu* Wcat  = (bfu*)((char*)d_ws + 41156608);          // 512*256*2   =    262,144
  bfu* Wredb = (bfu*)((char*)d_ws + 41418752);          //  64*256*2   =     32,768

  prep_kernel<<<5577, 256, 0, stream>>>(x, gamma, beta_ln, W_self, W_nei, W_red,
                                        C3, Wcat, Wredb);
  gemm_kernel<128, false><<<dim3(157, 4), 256, 0, stream>>>(
      C3 + 512, LDC3, Wcat, b_self, b_nei, (void*)C3, LDC3, NN);
  gather_kernel<<<5000, 256, 0, stream>>>(C3, coords, col, bmix, ctx);
  gemm_kernel<64, true><<<dim3(157, 1), 256, 0, stream>>>(
      ctx, DD, Wredb, b_red, b_red, d_out, 64, NN);
}